// Round 12
// baseline (140.227 us; speedup 1.0000x reference)
//
#include <hip/hip_runtime.h>
#include <cstdint>
#include <cstddef>

using u64 = unsigned long long;

namespace {
constexpr int kClassNum = 20;
constexpr int kBatch    = 64;
constexpr int kNBoxes   = 8732;
constexpr int kLast     = 65;   // 3*20+5
constexpr int kTopK     = 200;
// Reference NMS_MAX=400, but output = first 200 kept (stable top_k over
// non-increasing conf) and greedy keeps are prefix-causal => cap at 200.
constexpr int kNmsCap   = 200;
constexpr int kHist     = 1024; // conf histogram buckets
constexpr int kSelM     = 384;  // min candidates to select (consumed <= ~270)
constexpr int kCand     = 512;  // candidate pool for sort (pow2)
constexpr int kPool     = 2048; // static-prefilter pool cap (~870 expected)
constexpr float kPreT   = 0.9f; // static prefilter threshold (P(conf>0.9)~10%)
constexpr int kFThreads = 1024; // fused kernel block size (16 waves)
constexpr int kConfThreads = 256;
constexpr int kRows     = 128;  // rows per conf block
constexpr int kRBlocks  = (kNBoxes + kRows - 1) / kRows; // 69
constexpr int kNIter    = (kNBoxes + kFThreads - 1) / kFThreads; // 9
constexpr int kPoolIter = kPool / kFThreads; // 2
constexpr int kGroups   = kCand / 64; // 8
}

__device__ __forceinline__ int bucket_of_key(u64 k) {
  // top 16 bits of conf float (sign 0) - monotone in conf
  int b = (int)(unsigned)(k >> 48) - 0x3C23;
  return min(max(b, 0), kHist - 1);
}

// exact IoU per the reference op sequence (no contraction sites)
__device__ __forceinline__ float iou_f(float a0, float a1, float a2, float a3,
                                       float areaA, float4 bb) {
  const float ix1 = fmaxf(a0, bb.x);
  const float iy1 = fmaxf(a1, bb.y);
  const float ix2 = fminf(a2, bb.z);
  const float iy2 = fminf(a3, bb.w);
  const float inter = fmaxf(ix2 - ix1, 0.0f) * fmaxf(iy2 - iy1, 0.0f);
  const float areaB = fmaxf(bb.z - bb.x, 0.0f) * fmaxf(bb.w - bb.y, 0.0f);
  const float un = areaA + areaB - inter;
  return (un > 0.0f) ? inter / fmaxf(un, 1e-8f) : 0.0f;
}

__device__ __forceinline__ u64 readlane64(u64 x, int l) {
  const unsigned lo = (unsigned)__builtin_amdgcn_readlane((int)(unsigned)x, l);
  const unsigned hi = (unsigned)__builtin_amdgcn_readlane((int)(unsigned)(x >> 32), l);
  return ((u64)hi << 32) | (u64)lo;
}

// ---------------------------------------------------------------------------
// Kernel 1: conf. FULL-ROW contiguous float4 LDS staging (r8's measured-fast
// pattern: 1 KB/wave-instruction, DRAM-burst friendly). r11's column-trimmed
// chunked read fetched half the bytes at 1/7 the bandwidth (71 MB @ 0.86
// TB/s = 83 us vs 145 MB @ ~6 TB/s = 24 us): contiguity beats byte-count.
// Writes confs (fallback path) + prefiltered pool keys (conf > 0.9,
// ~870/item expected, cap 2048 unreachable) via 1 aggregated atomic/wave.
// Pool ORDER nondeterministic; SET deterministic; sort canonicalizes.
// ---------------------------------------------------------------------------
__global__ __launch_bounds__(kConfThreads) void conf_kernel(const float* __restrict__ y,
                                                            float* __restrict__ confs,
                                                            u64* __restrict__ pool,
                                                            int* __restrict__ gcnt) {
  __shared__ float tile[kRows * kLast]; // 33,280 B
  const int item = blockIdx.y;
  const int base = blockIdx.x * kRows;
  const int nb   = min(kRows, kNBoxes - base); // 128 or 28 -> nb*65 % 4 == 0
  const int tid  = threadIdx.x;
  const int lane = tid & 63;

  const float4* src4 = (const float4*)(y + ((size_t)item * kNBoxes + base) * kLast);
  float4* t4 = (float4*)tile;
  const int nf4 = nb * kLast / 4;
  for (int k = tid; k < nf4; k += kConfThreads) t4[k] = src4[k];
  __syncthreads();

  float conf = 0.0f;
  if (tid < nb) {
    const float* row = tile + tid * kLast;
    float best = row[20] * row[41];
#pragma unroll
    for (int c = 1; c < kClassNum; ++c) best = fmaxf(best, row[20 + c] * row[41 + c]);
    conf = best;
    confs[(size_t)item * kNBoxes + base + tid] = best;
  }

  const bool take = conf > kPreT;
  const u64 bal = __ballot(take);
  int wbase = 0;
  if (lane == 0 && bal) wbase = atomicAdd(&gcnt[item], __popcll(bal));
  wbase = __shfl(wbase, 0, 64);
  if (take) {
    const int pos = wbase + __popcll(bal & ((1ull << lane) - 1ull));
    if (pos < kPool)
      pool[(size_t)item * kPool + pos] =
          ((u64)__float_as_uint(conf) << 32) |
          (u64)(0xFFFFFFFFu - (unsigned)(base + tid));
  }
}

// ---------------------------------------------------------------------------
// Bitonic sort helpers: 512 u64 keys, elem i == tid (tid < 512 active; all
// threads hit the barriers). J<64 via shfl_xor, J>=64 via LDS (6 stages).
// ---------------------------------------------------------------------------
__device__ __forceinline__ u64 shfl_xor_u64(u64 x, int d) {
  int lo = __shfl_xor((int)(unsigned)x, d, 64);
  int hi = __shfl_xor((int)(unsigned)(x >> 32), d, 64);
  return ((u64)(unsigned)hi << 32) | (u64)(unsigned)lo;
}

__device__ __forceinline__ u64 cmpsel(u64 a, u64 b, bool keepmax) {
  u64 mx = a > b ? a : b;
  u64 mn = a > b ? b : a;
  return keepmax ? mx : mn;
}

template <int J, int K>
__device__ __forceinline__ void stage1(u64& k, int i, bool act, u64* buf) {
  if constexpr (J >= 64) {
    __syncthreads();
    if (act) buf[i] = k;
    __syncthreads();
    if (act) {
      const u64 pv = buf[i ^ J];
      const bool lower = (i & J) == 0;
      const bool desc  = (i & K) == 0;
      k = cmpsel(k, pv, desc == lower);
    }
  } else {
    const u64 pv = shfl_xor_u64(k, J);
    const bool lower = (i & J) == 0;
    const bool desc  = (i & K) == 0;
    k = cmpsel(k, pv, desc == lower);
  }
}

template <int K, int J>
__device__ __forceinline__ void cascade1(u64& k, int i, bool act, u64* buf) {
  stage1<J, K>(k, i, act, buf);
  if constexpr (J > 1) cascade1<K, (J >> 1)>(k, i, act, buf);
}

// ---------------------------------------------------------------------------
// Fused kernel (unchanged from r10/r11 - passed twice, ~35 us). Key source:
//   pool path (384 <= gcnt <= 2048): 2-iter scan of prefiltered keys.
//     EXACT: every excluded box has conf <= 0.9 < every pool member, and
//     gcnt >= kSelM forces T >= bucket(0.9), so selected set == full-scan set.
//   fallback: 9-iter scan of full confs array (any-data correctness).
// Then: LDS hist -> suffix scan -> threshold (suffix >= 384, +1 bump on
// kCand overflow) -> append -> bitonic sort 512 -> group-parallel greedy
// NMS (cap 200) with degenerate pruning, ballot columns, ctz resolve,
// pipelined gather. One block (16 waves) per item.
// ---------------------------------------------------------------------------
__global__ __launch_bounds__(kFThreads) void fused_kernel(const float* __restrict__ y,
                                                          const float* __restrict__ confs,
                                                          const u64* __restrict__ pool,
                                                          const int* __restrict__ gcnt,
                                                          float* __restrict__ out) {
  __shared__ u64    buf[kCand];         // 4 KB: candidate keys (sort + NMS src)
  __shared__ int    hist[kHist];        // 4 KB: counts -> suffix counts
  __shared__ int    wtot[16];
  __shared__ int    tails[16];
  __shared__ float4 selbox[kNmsCap];    // all kept boxes (output)
  __shared__ float2 selmeta[kNmsCap];   // cls, conf
  __shared__ float4 selact[kNmsCap];    // non-degenerate kept only (phase A)
  __shared__ float4 candbox[2][64];     // double-buffered candidate groups
  __shared__ float  candcls[2][64];
  __shared__ float  candconf[2][64];
  __shared__ u64    g_validm[2];
  __shared__ u64    supB[16];           // per-wave phase-A ballots
  __shared__ u64    colm[64];           // suppression column per group-cand j
  __shared__ int g_cnt, g_count, g_active, g_done, g_thr;

  const int item = blockIdx.x;
  const int tid  = threadIdx.x;
  const int lane = tid & 63;
  const int wv   = tid >> 6;  // 0..15
  const float* cbase = confs + (size_t)item * kNBoxes;
  const u64* pbase = pool + (size_t)item * kPool;
  const float* ybase = y + (size_t)item * kNBoxes * kLast;

  hist[tid] = 0;
  if (tid == 0) { g_cnt = 0; g_count = 0; g_active = 0; g_done = 0; g_thr = 0; }

  // ---- 1. load keys (pool fast path or full fallback) ----
  const int pcnt = gcnt[item];
  const bool usePool = (pcnt >= kSelM) && (pcnt <= kPool);
  u64 kv[kNIter];
  if (usePool) {
#pragma unroll
    for (int r = 0; r < kNIter; ++r) {
      const int i = tid + r * kFThreads;
      kv[r] = (r < kPoolIter && i < pcnt) ? pbase[i] : 0ull;
    }
  } else {
#pragma unroll
    for (int r = 0; r < kNIter; ++r) {
      const int i = tid + r * kFThreads;
      const float c = (i < kNBoxes) ? cbase[i] : 0.0f;
      kv[r] = (c > 0.01f)
                  ? (((u64)__float_as_uint(c) << 32) | (u64)(0xFFFFFFFFu - (unsigned)i))
                  : 0ull;
    }
  }
  __syncthreads(); // hist zeroed

  // ---- 2. LDS histogram ----
#pragma unroll
  for (int r = 0; r < kNIter; ++r)
    if (kv[r]) atomicAdd(&hist[bucket_of_key(kv[r])], 1);
  __syncthreads();

  // ---- 3. suffix scan via shfl (2 barriers): hist[b] := sum_{b'>=b} ----
  {
    int v = hist[tid];
#pragma unroll
    for (int off = 1; off < 64; off <<= 1) {
      const int o = __shfl_down(v, off, 64);
      if (lane + off < 64) v += o;
    }
    if (lane == 0) wtot[wv] = v;
    __syncthreads();
    if (tid < 16) {
      int t = wtot[tid];
#pragma unroll
      for (int off = 1; off < 16; off <<= 1) {
        const int o = __shfl_down(t, off, 64);
        if (tid + off < 16) t += o;
      }
      tails[tid] = t - wtot[tid]; // sum over waves strictly above
    }
    __syncthreads();
    hist[tid] = v + tails[wv];
  }
  __syncthreads();

  // ---- 4. threshold: largest T0 with suffix >= kSelM (else 0); bump if
  //         the boundary bucket would overflow the kCand sort pool ----
  {
    const int S  = hist[tid];
    const int Sn = (tid < kHist - 1) ? hist[tid + 1] : 0;
    if (S >= kSelM && Sn < kSelM) g_thr = tid; // at most one thread fires
  }
  __syncthreads();
  const int T0 = g_thr;
  const int T  = (hist[T0] > kCand && T0 < kHist - 1) ? T0 + 1 : T0;

  // ---- 5. wave-aggregated append of candidates (bucket >= T) ----
#pragma unroll
  for (int r = 0; r < kNIter; ++r) {
    const bool take = kv[r] && (bucket_of_key(kv[r]) >= T);
    const u64 bal = __ballot(take);
    int wbase = 0;
    if (lane == 0 && bal) wbase = atomicAdd(&g_cnt, __popcll(bal));
    wbase = __shfl(wbase, 0, 64);
    if (take) {
      const int pos = wbase + __popcll(bal & ((1ull << lane) - 1ull));
      if (pos < kCand) buf[pos] = kv[r];
    }
  }
  __syncthreads();
  const int ncand = min(g_cnt, kCand);
  for (int i2 = ncand + tid; i2 < kCand; i2 += kFThreads) buf[i2] = 0;
  __syncthreads();

  // ---- 6. bitonic sort 512 keys descending (unique keys -> canonical) ----
  {
    const bool act = tid < kCand;
    u64 k = act ? buf[tid] : 0ull;
    cascade1<2, 1>(k, tid, act, buf);
    cascade1<4, 2>(k, tid, act, buf);
    cascade1<8, 4>(k, tid, act, buf);
    cascade1<16, 8>(k, tid, act, buf);
    cascade1<32, 16>(k, tid, act, buf);
    cascade1<64, 32>(k, tid, act, buf);
    cascade1<128, 64>(k, tid, act, buf);
    cascade1<256, 128>(k, tid, act, buf);
    cascade1<512, 256>(k, tid, act, buf);
    __syncthreads(); // last LDS-stage reads done before write-back
    if (act) buf[tid] = k;
  }
  __syncthreads();

  // ---- 7. group-parallel greedy NMS (cap 200) ----
  auto gather = [&](int g, int slot) {
    float4 box = make_float4(0.f, 0.f, 0.f, 0.f);
    float cls = 0.f, cf = 0.f;
    int val = 0;
    if (g < kGroups) {
      const u64 key = buf[g * 64 + lane];
      if (key >> 32) {
        val = 1;
        cf = __uint_as_float((unsigned)(key >> 32));
        const unsigned idx = 0xFFFFFFFFu - (unsigned)key;
        const float* row = ybase + (size_t)idx * kLast;
        float best = row[20] * row[41];
        int cl = 1;
#pragma unroll
        for (int c = 1; c < kClassNum; ++c) {
          const float p = row[20 + c] * row[41 + c];
          if (p > best) { best = p; cl = c + 1; }
        }
        cls = (float)cl;
        const float c0 = fminf(fmaxf(row[61], 0.0f), 299.0f);
        const float c1 = fminf(fmaxf(row[62], 0.0f), 299.0f);
        const float c2 = fminf(fmaxf(row[63], 0.0f), 299.0f);
        const float c3 = fminf(fmaxf(row[64], 0.0f), 299.0f);
        box = make_float4(c0, c1, c2, c3);
      }
    }
    candbox[slot][lane]  = box;
    candcls[slot][lane]  = cls;
    candconf[slot][lane] = cf;
    const u64 vm = __ballot(val);
    if (lane == 0) g_validm[slot] = vm;
  };

  if (wv == 0) gather(0, 0);
  __syncthreads();

  int cur = 0;
  for (int g = 0; g < kGroups; ++g) {
    const int count = g_count;   // total kept
    const int act   = g_active;  // non-degenerate kept

    // phase A: max IoU vs ACTIVE kept set (16 wave partials -> ballots).
    // Degenerate candidate (areaA==0) has IoU==0 vs everything: skip.
    const float4 bx = candbox[cur][lane];
    const float a0 = bx.x, a1 = bx.y, a2 = bx.z, a3 = bx.w;
    const float areaA = fmaxf(a2 - a0, 0.0f) * fmaxf(a3 - a1, 0.0f);
    float m = 0.0f;
    if (areaA > 0.0f) {
      for (int s = wv; s < act; s += 16) m = fmaxf(m, iou_f(a0, a1, a2, a3, areaA, selact[s]));
    }
    {
      const u64 pb = __ballot(m > 0.45f);
      if (lane == 0) supB[wv] = pb;
    }

    // phase B: suppression COLUMNS. Wave wv handles j = 4wv..4wv+3:
    // colm[j] bit L = (j < L) && IoU(cand L, cand j) > 0.45.
    // Degenerate j suppresses nothing (IoU==0 exactly): skip (uniform branch).
#pragma unroll
    for (int jj = 0; jj < 4; ++jj) {
      const int j = wv * 4 + jj;
      const float4 bb = candbox[cur][j]; // wave-uniform -> broadcast
      const float areaB = fmaxf(bb.z - bb.x, 0.0f) * fmaxf(bb.w - bb.y, 0.0f);
      u64 cm = 0ull;
      if (areaB > 0.0f) {
        const float iou = iou_f(a0, a1, a2, a3, areaA, bb);
        cm = __ballot((j < lane) && (iou > 0.45f));
      }
      if (lane == 0) colm[j] = cm;
    }
    __syncthreads();

    // concurrent: wave 1 gathers next group; wave 0 resolves current group
    if (wv == 1) gather(g + 1, cur ^ 1);
    if (wv == 0) {
      u64 supm = 0ull;
#pragma unroll
      for (int ww = 0; ww < 16; ++ww) supm |= supB[ww];
      const u64 mycol  = colm[lane];     // column of candidate `lane`
      const u64 validm = g_validm[cur];

      u64 avail = validm & ~supm;        // will-be-kept frontier
      u64 keptm = 0ull;
      int cnt2 = count;
      int done = 0;
      while (avail) {
        const int j = __builtin_ctzll(avail); // lowest remaining = greedy order
        keptm |= (1ull << j);
        if (++cnt2 >= kNmsCap) { done = 1; break; }
        const u64 cj = readlane64(mycol, j);  // whom j suppresses
        avail &= ~(cj | (1ull << j));
      }
      if (validm != ~0ull) done = 1; // group had invalid => rest all invalid

      const u64 below = (1ull << lane) - 1ull;
      const u64 actm = keptm & __ballot(areaA > 0.0f);
      if ((keptm >> lane) & 1ull) {
        const int wdx = count + __popcll(keptm & below);
        if (wdx < kNmsCap) {
          selbox[wdx]  = bx;
          selmeta[wdx] = make_float2(candcls[cur][lane], candconf[cur][lane]);
        }
      }
      if ((actm >> lane) & 1ull) {
        const int adx = act + __popcll(actm & below);
        if (adx < kNmsCap) selact[adx] = bx;
      }
      if (lane == 0) {
        g_count  = min(cnt2, kNmsCap);
        g_active = min(act + __popcll(actm), kNmsCap);
        g_done   = done;
      }
    }
    __syncthreads();
    if (g_done) break;
    cur ^= 1;
  }

  // ---- 8. emit first 200 selected rows, zero-padded ----
  const int count = g_count;
  float* obase = out + (size_t)item * kTopK * 6;
  for (int slot = tid; slot < kTopK; slot += kFThreads) {
    float* o = obase + (size_t)slot * 6;
    if (slot < count) {
      const float4 bsel = selbox[slot];
      const float2 mta  = selmeta[slot];
      o[0] = mta.x; o[1] = mta.y; o[2] = bsel.x; o[3] = bsel.y; o[4] = bsel.z; o[5] = bsel.w;
    } else {
      o[0] = 0.0f; o[1] = 0.0f; o[2] = 0.0f; o[3] = 0.0f; o[4] = 0.0f; o[5] = 0.0f;
    }
  }
}

// ---------------------------------------------------------------------------
extern "C" void kernel_launch(void* const* d_in, const int* in_sizes, int n_in,
                              void* d_out, int out_size, void* d_ws, size_t ws_size,
                              hipStream_t stream) {
  const float* y = (const float*)d_in[0];
  float* out = (float*)d_out;

  // ws layout: confs [64*8732 f32] | pool [64*2048 u64] | gcnt [64 i32]
  float* confs = (float*)d_ws;
  u64* pool = (u64*)(confs + (size_t)kBatch * kNBoxes);
  int* gcnt = (int*)(pool + (size_t)kBatch * kPool);

  hipMemsetAsync(gcnt, 0, kBatch * sizeof(int), stream);
  dim3 cgrid(kRBlocks, kBatch);
  conf_kernel<<<cgrid, kConfThreads, 0, stream>>>(y, confs, pool, gcnt);
  fused_kernel<<<kBatch, kFThreads, 0, stream>>>(y, confs, pool, gcnt, out);
}

// Round 13
// 66.329 us; speedup vs baseline: 2.1141x; 2.1141x over previous
//
#include <hip/hip_runtime.h>
#include <cstdint>
#include <cstddef>

using u64 = unsigned long long;

namespace {
constexpr int kClassNum = 20;
constexpr int kBatch    = 64;
constexpr int kNBoxes   = 8732;
constexpr int kLast     = 65;   // 3*20+5
constexpr int kTopK     = 200;
// Reference NMS_MAX=400, but output = first 200 kept (stable top_k over
// non-increasing conf) and greedy keeps are prefix-causal => cap at 200.
constexpr int kNmsCap   = 200;
constexpr int kHist     = 1024; // conf histogram buckets
constexpr int kSelM     = 384;  // min candidates to select (consumed <= ~270)
constexpr int kCand     = 512;  // candidate pool for sort (pow2)
constexpr float kPreT   = 0.9f; // static prefilter threshold (P(conf>0.9)~10%)
constexpr int kB09      = 0x3F66 - 0x3C23; // 835: bucket containing 0.9
constexpr int kFThreads = 1024; // fused kernel block size (16 waves)
constexpr int kConfThreads = 256;
constexpr int kRows     = 128;  // rows per conf block
constexpr int kRBlocks  = (kNBoxes + kRows - 1) / kRows; // 69
constexpr int kSlots    = 32;   // fixed pool slots per conf block (mean takes 12.7, sigma 3.4)
constexpr int kPoolW    = kRBlocks * kSlots; // 2208 per item
constexpr int kNIter    = (kNBoxes + kFThreads - 1) / kFThreads; // 9
constexpr int kPWIter   = (kPoolW + kFThreads - 1) / kFThreads;  // 3
constexpr int kGroups   = kCand / 64; // 8
}

__device__ __forceinline__ int bucket_of_key(u64 k) {
  // top 16 bits of conf float (sign 0) - monotone in conf
  int b = (int)(unsigned)(k >> 48) - 0x3C23;
  return min(max(b, 0), kHist - 1);
}

// exact IoU per the reference op sequence (no contraction sites)
__device__ __forceinline__ float iou_f(float a0, float a1, float a2, float a3,
                                       float areaA, float4 bb) {
  const float ix1 = fmaxf(a0, bb.x);
  const float iy1 = fmaxf(a1, bb.y);
  const float ix2 = fminf(a2, bb.z);
  const float iy2 = fminf(a3, bb.w);
  const float inter = fmaxf(ix2 - ix1, 0.0f) * fmaxf(iy2 - iy1, 0.0f);
  const float areaB = fmaxf(bb.z - bb.x, 0.0f) * fmaxf(bb.w - bb.y, 0.0f);
  const float un = areaA + areaB - inter;
  return (un > 0.0f) ? inter / fmaxf(un, 1e-8f) : 0.0f;
}

__device__ __forceinline__ u64 readlane64(u64 x, int l) {
  const unsigned lo = (unsigned)__builtin_amdgcn_readlane((int)(unsigned)x, l);
  const unsigned hi = (unsigned)__builtin_amdgcn_readlane((int)(unsigned)(x >> 32), l);
  return ((u64)hi << 32) | (u64)lo;
}

// ---------------------------------------------------------------------------
// Kernel 1: conf. Full-row contiguous float4 LDS staging (r8's fast pattern).
// NO GLOBAL ATOMICS: r10-r12's conf slowness (~+80 us) was 17,664 wave-
// atomicAdds on gcnt[64] = 4 cache lines ping-ponging across 8 XCDs, not the
// read pattern. Compaction is now deterministic: each block owns a FIXED
// 32-slot pool region; block-local ranks via ballot + LDS wave counts;
// unused slots zero-filled; bcnt[item][blk] = take count (plain store).
// Overflow (total > 32, P ~ 6e-9/block) detected by fused -> full fallback.
// ---------------------------------------------------------------------------
__global__ __launch_bounds__(kConfThreads) void conf_kernel(const float* __restrict__ y,
                                                            float* __restrict__ confs,
                                                            u64* __restrict__ pool,
                                                            int* __restrict__ bcnt) {
  __shared__ float tile[kRows * kLast]; // 33,280 B
  __shared__ int wcnt[kConfThreads / 64];
  const int item = blockIdx.y;
  const int blk  = blockIdx.x;
  const int base = blk * kRows;
  const int nb   = min(kRows, kNBoxes - base); // 128 or 28 -> nb*65 % 4 == 0
  const int tid  = threadIdx.x;
  const int lane = tid & 63;
  const int wv   = tid >> 6; // 0..3

  const float4* src4 = (const float4*)(y + ((size_t)item * kNBoxes + base) * kLast);
  float4* t4 = (float4*)tile;
  const int nf4 = nb * kLast / 4;
  for (int k = tid; k < nf4; k += kConfThreads) t4[k] = src4[k];
  __syncthreads();

  float conf = 0.0f;
  if (tid < nb) {
    const float* row = tile + tid * kLast;
    float best = row[20] * row[41];
#pragma unroll
    for (int c = 1; c < kClassNum; ++c) best = fmaxf(best, row[20 + c] * row[41 + c]);
    conf = best;
    confs[(size_t)item * kNBoxes + base + tid] = best;
  }

  const bool take = conf > kPreT;
  const u64 bal = __ballot(take);
  if (lane == 0) wcnt[wv] = __popcll(bal);
  __syncthreads();
  int pre = 0, total = 0;
#pragma unroll
  for (int w = 0; w < kConfThreads / 64; ++w) {
    const int c = wcnt[w];
    if (w < wv) pre += c;
    total += c;
  }
  u64* pblk = pool + (size_t)item * kPoolW + blk * kSlots;
  if (take) {
    const int rank = pre + __popcll(bal & ((1ull << lane) - 1ull));
    if (rank < kSlots)
      pblk[rank] = ((u64)__float_as_uint(conf) << 32) |
                   (u64)(0xFFFFFFFFu - (unsigned)(base + tid));
  }
  if (tid < kSlots && tid >= total) pblk[tid] = 0; // zero-fill unused slots
  if (tid == 0) bcnt[item * kRBlocks + blk] = total;
}

// ---------------------------------------------------------------------------
// Bitonic sort helpers: 512 u64 keys, elem i == tid (tid < 512 active; all
// threads hit the barriers). J<64 via shfl_xor, J>=64 via LDS (6 stages).
// ---------------------------------------------------------------------------
__device__ __forceinline__ u64 shfl_xor_u64(u64 x, int d) {
  int lo = __shfl_xor((int)(unsigned)x, d, 64);
  int hi = __shfl_xor((int)(unsigned)(x >> 32), d, 64);
  return ((u64)(unsigned)hi << 32) | (u64)(unsigned)lo;
}

__device__ __forceinline__ u64 cmpsel(u64 a, u64 b, bool keepmax) {
  u64 mx = a > b ? a : b;
  u64 mn = a > b ? b : a;
  return keepmax ? mx : mn;
}

template <int J, int K>
__device__ __forceinline__ void stage1(u64& k, int i, bool act, u64* buf) {
  if constexpr (J >= 64) {
    __syncthreads();
    if (act) buf[i] = k;
    __syncthreads();
    if (act) {
      const u64 pv = buf[i ^ J];
      const bool lower = (i & J) == 0;
      const bool desc  = (i & K) == 0;
      k = cmpsel(k, pv, desc == lower);
    }
  } else {
    const u64 pv = shfl_xor_u64(k, J);
    const bool lower = (i & J) == 0;
    const bool desc  = (i & K) == 0;
    k = cmpsel(k, pv, desc == lower);
  }
}

template <int K, int J>
__device__ __forceinline__ void cascade1(u64& k, int i, bool act, u64* buf) {
  stage1<J, K>(k, i, act, buf);
  if constexpr (J > 1) cascade1<K, (J >> 1)>(k, i, act, buf);
}

// ---------------------------------------------------------------------------
// Fused kernel. Key source (block-uniform):
//   pool path: 3-iter scan of the fixed-slot prefiltered pool. EXACT iff
//     no block overflowed AND hist[kB09+1] >= kSelM (threshold then lands
//     strictly above the 0.9-boundary bucket, where pool == full scan).
//   else: 9-iter fallback scan of full confs (redo hist if needed).
// Then: suffix scan -> threshold (suffix >= 384, +1 bump on kCand overflow)
// -> append -> bitonic sort 512 -> group-parallel greedy NMS (cap 200) with
// degenerate pruning, ballot columns, ctz resolve, pipelined gather.
// ---------------------------------------------------------------------------
__global__ __launch_bounds__(kFThreads) void fused_kernel(const float* __restrict__ y,
                                                          const float* __restrict__ confs,
                                                          const u64* __restrict__ pool,
                                                          const int* __restrict__ bcnt,
                                                          float* __restrict__ out) {
  __shared__ u64    buf[kCand];         // 4 KB: candidate keys (sort + NMS src)
  __shared__ int    hist[kHist];        // 4 KB: counts -> suffix counts
  __shared__ int    wtot[16];
  __shared__ int    tails[16];
  __shared__ float4 selbox[kNmsCap];    // all kept boxes (output)
  __shared__ float2 selmeta[kNmsCap];   // cls, conf
  __shared__ float4 selact[kNmsCap];    // non-degenerate kept only (phase A)
  __shared__ float4 candbox[2][64];     // double-buffered candidate groups
  __shared__ float  candcls[2][64];
  __shared__ float  candconf[2][64];
  __shared__ u64    g_validm[2];
  __shared__ u64    supB[16];           // per-wave phase-A ballots
  __shared__ u64    colm[64];           // suppression column per group-cand j
  __shared__ int g_cnt, g_count, g_active, g_done, g_thr, g_bad;

  const int item = blockIdx.x;
  const int tid  = threadIdx.x;
  const int lane = tid & 63;
  const int wv   = tid >> 6;  // 0..15
  const float* cbase = confs + (size_t)item * kNBoxes;
  const u64* pbase = pool + (size_t)item * kPoolW;
  const float* ybase = y + (size_t)item * kNBoxes * kLast;

  hist[tid] = 0;
  if (tid == 0) { g_cnt = 0; g_count = 0; g_active = 0; g_done = 0; g_thr = 0; g_bad = 0; }
  __syncthreads();
  if (tid < kRBlocks && bcnt[item * kRBlocks + tid] > kSlots) g_bad = 1;
  __syncthreads();
  const bool pooled = (g_bad == 0);

  u64 kv[kNIter];
  auto load_fallback = [&]() {
#pragma unroll
    for (int r = 0; r < kNIter; ++r) {
      const int i = tid + r * kFThreads;
      const float c = (i < kNBoxes) ? cbase[i] : 0.0f;
      kv[r] = (c > 0.01f)
                  ? (((u64)__float_as_uint(c) << 32) | (u64)(0xFFFFFFFFu - (unsigned)i))
                  : 0ull;
    }
  };
  auto build_hist = [&]() {
#pragma unroll
    for (int r = 0; r < kNIter; ++r)
      if (kv[r]) atomicAdd(&hist[bucket_of_key(kv[r])], 1);
    __syncthreads();
  };
  auto suffix_scan = [&]() {
    int v = hist[tid];
#pragma unroll
    for (int off = 1; off < 64; off <<= 1) {
      const int o = __shfl_down(v, off, 64);
      if (lane + off < 64) v += o;
    }
    if (lane == 0) wtot[wv] = v;
    __syncthreads();
    if (tid < 16) {
      int t = wtot[tid];
#pragma unroll
      for (int off = 1; off < 16; off <<= 1) {
        const int o = __shfl_down(t, off, 64);
        if (tid + off < 16) t += o;
      }
      tails[tid] = t - wtot[tid]; // sum over waves strictly above
    }
    __syncthreads();
    hist[tid] = v + tails[wv];
    __syncthreads();
  };

  // ---- 1. load keys + histogram (pool fast path, exactness-guarded) ----
  if (pooled) {
#pragma unroll
    for (int r = 0; r < kNIter; ++r) {
      const int i = tid + r * kFThreads;
      kv[r] = (r < kPWIter && i < kPoolW) ? pbase[i] : 0ull;
    }
  } else {
    load_fallback();
  }
  build_hist();
  suffix_scan();

  // pool path exact iff enough mass strictly above the 0.9-boundary bucket
  if (pooled && hist[kB09 + 1] < kSelM) {
    hist[tid] = 0;
    __syncthreads();
    load_fallback();
    build_hist();
    suffix_scan();
  }

  // ---- 2. threshold: largest T0 with suffix >= kSelM (else 0); bump if
  //         the boundary bucket would overflow the kCand sort pool ----
  {
    const int S  = hist[tid];
    const int Sn = (tid < kHist - 1) ? hist[tid + 1] : 0;
    if (S >= kSelM && Sn < kSelM) g_thr = tid; // at most one thread fires
  }
  __syncthreads();
  const int T0 = g_thr;
  const int T  = (hist[T0] > kCand && T0 < kHist - 1) ? T0 + 1 : T0;

  // ---- 3. wave-aggregated append of candidates (bucket >= T) ----
#pragma unroll
  for (int r = 0; r < kNIter; ++r) {
    const bool take = kv[r] && (bucket_of_key(kv[r]) >= T);
    const u64 bal = __ballot(take);
    int wbase = 0;
    if (lane == 0 && bal) wbase = atomicAdd(&g_cnt, __popcll(bal));
    wbase = __shfl(wbase, 0, 64);
    if (take) {
      const int pos = wbase + __popcll(bal & ((1ull << lane) - 1ull));
      if (pos < kCand) buf[pos] = kv[r];
    }
  }
  __syncthreads();
  const int ncand = min(g_cnt, kCand);
  for (int i2 = ncand + tid; i2 < kCand; i2 += kFThreads) buf[i2] = 0;
  __syncthreads();

  // ---- 4. bitonic sort 512 keys descending (unique keys -> canonical) ----
  {
    const bool act = tid < kCand;
    u64 k = act ? buf[tid] : 0ull;
    cascade1<2, 1>(k, tid, act, buf);
    cascade1<4, 2>(k, tid, act, buf);
    cascade1<8, 4>(k, tid, act, buf);
    cascade1<16, 8>(k, tid, act, buf);
    cascade1<32, 16>(k, tid, act, buf);
    cascade1<64, 32>(k, tid, act, buf);
    cascade1<128, 64>(k, tid, act, buf);
    cascade1<256, 128>(k, tid, act, buf);
    cascade1<512, 256>(k, tid, act, buf);
    __syncthreads(); // last LDS-stage reads done before write-back
    if (act) buf[tid] = k;
  }
  __syncthreads();

  // ---- 5. group-parallel greedy NMS (cap 200) ----
  auto gather = [&](int g, int slot) {
    float4 box = make_float4(0.f, 0.f, 0.f, 0.f);
    float cls = 0.f, cf = 0.f;
    int val = 0;
    if (g < kGroups) {
      const u64 key = buf[g * 64 + lane];
      if (key >> 32) {
        val = 1;
        cf = __uint_as_float((unsigned)(key >> 32));
        const unsigned idx = 0xFFFFFFFFu - (unsigned)key;
        const float* row = ybase + (size_t)idx * kLast;
        float best = row[20] * row[41];
        int cl = 1;
#pragma unroll
        for (int c = 1; c < kClassNum; ++c) {
          const float p = row[20 + c] * row[41 + c];
          if (p > best) { best = p; cl = c + 1; }
        }
        cls = (float)cl;
        const float c0 = fminf(fmaxf(row[61], 0.0f), 299.0f);
        const float c1 = fminf(fmaxf(row[62], 0.0f), 299.0f);
        const float c2 = fminf(fmaxf(row[63], 0.0f), 299.0f);
        const float c3 = fminf(fmaxf(row[64], 0.0f), 299.0f);
        box = make_float4(c0, c1, c2, c3);
      }
    }
    candbox[slot][lane]  = box;
    candcls[slot][lane]  = cls;
    candconf[slot][lane] = cf;
    const u64 vm = __ballot(val);
    if (lane == 0) g_validm[slot] = vm;
  };

  if (wv == 0) gather(0, 0);
  __syncthreads();

  int cur = 0;
  for (int g = 0; g < kGroups; ++g) {
    const int count = g_count;   // total kept
    const int act   = g_active;  // non-degenerate kept

    // phase A: max IoU vs ACTIVE kept set (16 wave partials -> ballots).
    const float4 bx = candbox[cur][lane];
    const float a0 = bx.x, a1 = bx.y, a2 = bx.z, a3 = bx.w;
    const float areaA = fmaxf(a2 - a0, 0.0f) * fmaxf(a3 - a1, 0.0f);
    float m = 0.0f;
    if (areaA > 0.0f) {
      for (int s = wv; s < act; s += 16) m = fmaxf(m, iou_f(a0, a1, a2, a3, areaA, selact[s]));
    }
    {
      const u64 pb = __ballot(m > 0.45f);
      if (lane == 0) supB[wv] = pb;
    }

    // phase B: suppression COLUMNS (wave wv handles j = 4wv..4wv+3)
#pragma unroll
    for (int jj = 0; jj < 4; ++jj) {
      const int j = wv * 4 + jj;
      const float4 bb = candbox[cur][j]; // wave-uniform -> broadcast
      const float areaB = fmaxf(bb.z - bb.x, 0.0f) * fmaxf(bb.w - bb.y, 0.0f);
      u64 cm = 0ull;
      if (areaB > 0.0f) {
        const float iou = iou_f(a0, a1, a2, a3, areaA, bb);
        cm = __ballot((j < lane) && (iou > 0.45f));
      }
      if (lane == 0) colm[j] = cm;
    }
    __syncthreads();

    // concurrent: wave 1 gathers next group; wave 0 resolves current group
    if (wv == 1) gather(g + 1, cur ^ 1);
    if (wv == 0) {
      u64 supm = 0ull;
#pragma unroll
      for (int ww = 0; ww < 16; ++ww) supm |= supB[ww];
      const u64 mycol  = colm[lane];     // column of candidate `lane`
      const u64 validm = g_validm[cur];

      u64 avail = validm & ~supm;        // will-be-kept frontier
      u64 keptm = 0ull;
      int cnt2 = count;
      int done = 0;
      while (avail) {
        const int j = __builtin_ctzll(avail); // lowest remaining = greedy order
        keptm |= (1ull << j);
        if (++cnt2 >= kNmsCap) { done = 1; break; }
        const u64 cj = readlane64(mycol, j);  // whom j suppresses
        avail &= ~(cj | (1ull << j));
      }
      if (validm != ~0ull) done = 1; // group had invalid => rest all invalid

      const u64 below = (1ull << lane) - 1ull;
      const u64 actm = keptm & __ballot(areaA > 0.0f);
      if ((keptm >> lane) & 1ull) {
        const int wdx = count + __popcll(keptm & below);
        if (wdx < kNmsCap) {
          selbox[wdx]  = bx;
          selmeta[wdx] = make_float2(candcls[cur][lane], candconf[cur][lane]);
        }
      }
      if ((actm >> lane) & 1ull) {
        const int adx = act + __popcll(actm & below);
        if (adx < kNmsCap) selact[adx] = bx;
      }
      if (lane == 0) {
        g_count  = min(cnt2, kNmsCap);
        g_active = min(act + __popcll(actm), kNmsCap);
        g_done   = done;
      }
    }
    __syncthreads();
    if (g_done) break;
    cur ^= 1;
  }

  // ---- 6. emit first 200 selected rows, zero-padded ----
  const int count = g_count;
  float* obase = out + (size_t)item * kTopK * 6;
  for (int slot = tid; slot < kTopK; slot += kFThreads) {
    float* o = obase + (size_t)slot * 6;
    if (slot < count) {
      const float4 bsel = selbox[slot];
      const float2 mta  = selmeta[slot];
      o[0] = mta.x; o[1] = mta.y; o[2] = bsel.x; o[3] = bsel.y; o[4] = bsel.z; o[5] = bsel.w;
    } else {
      o[0] = 0.0f; o[1] = 0.0f; o[2] = 0.0f; o[3] = 0.0f; o[4] = 0.0f; o[5] = 0.0f;
    }
  }
}

// ---------------------------------------------------------------------------
extern "C" void kernel_launch(void* const* d_in, const int* in_sizes, int n_in,
                              void* d_out, int out_size, void* d_ws, size_t ws_size,
                              hipStream_t stream) {
  const float* y = (const float*)d_in[0];
  float* out = (float*)d_out;

  // ws layout: confs [64*8732 f32] | pool [64*2208 u64] | bcnt [64*69 i32]
  float* confs = (float*)d_ws;
  u64* pool = (u64*)(confs + (size_t)kBatch * kNBoxes);
  int* bcnt = (int*)(pool + (size_t)kBatch * kPoolW);

  dim3 cgrid(kRBlocks, kBatch);
  conf_kernel<<<cgrid, kConfThreads, 0, stream>>>(y, confs, pool, bcnt);
  fused_kernel<<<kBatch, kFThreads, 0, stream>>>(y, confs, pool, bcnt, out);
}